// Round 9
// baseline (392.297 us; speedup 1.0000x reference)
//
#include <hip/hip_runtime.h>
#include <math.h>

#define B_   8
#define N_   16384
#define M_   64
#define C_   192
#define RC_  16
#define ATS  68   // at_t stride (floats): 16B-aligned float4 reads, 2-way bank max

#define FMA4(acc, s, v) \
    acc.x = fmaf(s, v.x, acc.x); acc.y = fmaf(s, v.y, acc.y); \
    acc.z = fmaf(s, v.z, acc.z); acc.w = fmaf(s, v.w, acc.w)

// ---------------------------------------------------------------------------
// K_prep: fused  v = dict@wv+b -> conv3x1+GELU -> ws_vg ; k = l2n(LN(...)) -> ws_k
// (unchanged — verified correct)
// ---------------------------------------------------------------------------
__global__ __launch_bounds__(256) void k_prep_kernel(
    const float* __restrict__ dict,
    const float* __restrict__ wv_w, const float* __restrict__ wv_b,
    const float* __restrict__ conv_w, const float* __restrict__ conv_b,
    const float* __restrict__ wk_w, const float* __restrict__ wk_b,
    const float* __restrict__ kn_g, const float* __restrict__ kn_b,
    float* __restrict__ ws_vg, float* __restrict__ ws_k)
{
    const int b   = blockIdx.x >> 6;
    const int m   = blockIdx.x & 63;
    const int tid = threadIdx.x;
    const float* d0 = dict + (b * M_ + m) * C_;

    if (tid < 192) {
        const int c = tid;
        const bool hm = (m > 0), hp = (m < M_ - 1);
        const float* dm = hm ? d0 - C_ : d0;
        const float* dp = hp ? d0 + C_ : d0;
        float am = 0.f, ac = 0.f, ap = 0.f;
        #pragma unroll 4
        for (int d = 0; d < C_; ++d) {
            const float w = wv_w[d * C_ + c];
            am = fmaf(dm[d], w, am);
            ac = fmaf(d0[d], w, ac);
            ap = fmaf(dp[d], w, ap);
        }
        const float bia = wv_b[c];
        const float up = hm ? (am + bia) : 0.f;
        const float ct = ac + bia;
        const float dn = hp ? (ap + bia) : 0.f;
        float t = conv_b[c];
        t = fmaf(up, conv_w[c*9 + 1], t);
        t = fmaf(ct, conv_w[c*9 + 4], t);
        t = fmaf(dn, conv_w[c*9 + 7], t);
        ws_vg[(b * M_ + m) * C_ + c] = 0.5f * t * (1.0f + erff(t * 0.70710678118654752f));
    } else if (tid < 196) {
        const int j4 = tid - 192;
        const int c0 = j4 * 4;
        float a0 = wk_b[c0+0], a1 = wk_b[c0+1], a2 = wk_b[c0+2], a3 = wk_b[c0+3];
        #pragma unroll 4
        for (int d4 = 0; d4 < C_/4; ++d4) {
            const float4 xv = ((const float4*)d0)[d4];
            const float4 w0 = *(const float4*)&wk_w[(d4*4+0)*RC_ + c0];
            const float4 w1 = *(const float4*)&wk_w[(d4*4+1)*RC_ + c0];
            const float4 w2 = *(const float4*)&wk_w[(d4*4+2)*RC_ + c0];
            const float4 w3 = *(const float4*)&wk_w[(d4*4+3)*RC_ + c0];
            a0 = fmaf(xv.x, w0.x, a0); a1 = fmaf(xv.x, w0.y, a1); a2 = fmaf(xv.x, w0.z, a2); a3 = fmaf(xv.x, w0.w, a3);
            a0 = fmaf(xv.y, w1.x, a0); a1 = fmaf(xv.y, w1.y, a1); a2 = fmaf(xv.y, w1.z, a2); a3 = fmaf(xv.y, w1.w, a3);
            a0 = fmaf(xv.z, w2.x, a0); a1 = fmaf(xv.z, w2.y, a1); a2 = fmaf(xv.z, w2.z, a2); a3 = fmaf(xv.z, w2.w, a3);
            a0 = fmaf(xv.w, w3.x, a0); a1 = fmaf(xv.w, w3.y, a1); a2 = fmaf(xv.w, w3.z, a2); a3 = fmaf(xv.w, w3.w, a3);
        }
        float s  = a0 + a1 + a2 + a3;
        float ss = a0*a0 + a1*a1 + a2*a2 + a3*a3;
        s  += __shfl_xor(s, 1);  s  += __shfl_xor(s, 2);
        ss += __shfl_xor(ss, 1); ss += __shfl_xor(ss, 2);
        const float mu   = s * (1.0f/16.0f);
        const float var  = ss * (1.0f/16.0f) - mu*mu;
        const float rstd = rsqrtf(var + 1e-5f);
        const float4 g4 = *(const float4*)&kn_g[c0];
        const float4 b4 = *(const float4*)&kn_b[c0];
        const float y0 = (a0 - mu) * rstd * g4.x + b4.x;
        const float y1 = (a1 - mu) * rstd * g4.y + b4.y;
        const float y2 = (a2 - mu) * rstd * g4.z + b4.z;
        const float y3 = (a3 - mu) * rstd * g4.w + b4.w;
        float n2 = y0*y0 + y1*y1 + y2*y2 + y3*y3;
        n2 += __shfl_xor(n2, 1); n2 += __shfl_xor(n2, 2);
        const float inv = 1.0f / fmaxf(sqrtf(n2), 1e-12f);
        float4 o; o.x = y0*inv; o.y = y1*inv; o.z = y2*inv; o.w = y3*inv;
        *(float4*)&ws_k[(b * M_ + m) * RC_ + c0] = o;
    }
}

// ---------------------------------------------------------------------------
// K_q: phases (a)+(b) only. ZERO LDS, ZERO barriers -> occupancy VGPR-bound
//   (~16-20 waves/CU vs 8 in the monolith) to hide the x-load latency.
//   thread (r=tid>>2, j4): quad computes one row; k read from global
//   (4 KB, L1-resident, quad-broadcast). m-ownership = j4*16+mm so the attn
//   store is 4 coalesced float4.
// ---------------------------------------------------------------------------
__global__ __launch_bounds__(256, 2) void k_q_kernel(
    const float* __restrict__ x, const float* __restrict__ ws_k,
    const float* __restrict__ wq_w, const float* __restrict__ wq_b,
    const float* __restrict__ qn_g, const float* __restrict__ qn_b,
    const float* __restrict__ temp, float* __restrict__ attn_out)
{
    const int tid   = threadIdx.x;
    const int b     = blockIdx.x >> 8;
    const int n0    = (blockIdx.x & 255) * M_;
    const int lane  = tid & 63;
    const int lbase = lane & ~3;
    const int r  = tid >> 2;
    const int j4 = tid & 3;
    const int c0 = j4 * 4;

    // ---- phase (a): q projection + LN + l2norm ----
    const float* xr = x + (size_t)(b * N_ + n0 + r) * C_;
    float a0 = wq_b[c0+0], a1 = wq_b[c0+1], a2 = wq_b[c0+2], a3 = wq_b[c0+3];
    #pragma unroll 4
    for (int d4 = 0; d4 < C_/4; ++d4) {
        const float4 xv = ((const float4*)xr)[d4];
        const float4 w0 = *(const float4*)&wq_w[(d4*4+0)*RC_ + c0];
        const float4 w1 = *(const float4*)&wq_w[(d4*4+1)*RC_ + c0];
        const float4 w2 = *(const float4*)&wq_w[(d4*4+2)*RC_ + c0];
        const float4 w3 = *(const float4*)&wq_w[(d4*4+3)*RC_ + c0];
        a0 = fmaf(xv.x, w0.x, a0); a1 = fmaf(xv.x, w0.y, a1); a2 = fmaf(xv.x, w0.z, a2); a3 = fmaf(xv.x, w0.w, a3);
        a0 = fmaf(xv.y, w1.x, a0); a1 = fmaf(xv.y, w1.y, a1); a2 = fmaf(xv.y, w1.z, a2); a3 = fmaf(xv.y, w1.w, a3);
        a0 = fmaf(xv.z, w2.x, a0); a1 = fmaf(xv.z, w2.y, a1); a2 = fmaf(xv.z, w2.z, a2); a3 = fmaf(xv.z, w2.w, a3);
        a0 = fmaf(xv.w, w3.x, a0); a1 = fmaf(xv.w, w3.y, a1); a2 = fmaf(xv.w, w3.z, a2); a3 = fmaf(xv.w, w3.w, a3);
    }
    float4 q[4];
    {
        float s  = a0 + a1 + a2 + a3;
        float ss = a0*a0 + a1*a1 + a2*a2 + a3*a3;
        s  += __shfl_xor(s, 1);  s  += __shfl_xor(s, 2);
        ss += __shfl_xor(ss, 1); ss += __shfl_xor(ss, 2);
        const float mu   = s * (1.0f/16.0f);
        const float var  = ss * (1.0f/16.0f) - mu*mu;
        const float rstd = rsqrtf(var + 1e-5f);
        const float4 g4 = *(const float4*)&qn_g[c0];
        const float4 b4 = *(const float4*)&qn_b[c0];
        const float y0 = (a0 - mu) * rstd * g4.x + b4.x;
        const float y1 = (a1 - mu) * rstd * g4.y + b4.y;
        const float y2 = (a2 - mu) * rstd * g4.z + b4.z;
        const float y3 = (a3 - mu) * rstd * g4.w + b4.w;
        float n2 = y0*y0 + y1*y1 + y2*y2 + y3*y3;
        n2 += __shfl_xor(n2, 1); n2 += __shfl_xor(n2, 2);
        const float inv = 1.0f / fmaxf(sqrtf(n2), 1e-12f);
        float4 o; o.x = y0*inv; o.y = y1*inv; o.z = y2*inv; o.w = y3*inv;
        #pragma unroll
        for (int j = 0; j < 4; ++j) {
            q[j].x = __shfl(o.x, lbase + j);
            q[j].y = __shfl(o.y, lbase + j);
            q[j].z = __shfl(o.z, lbase + j);
            q[j].w = __shfl(o.w, lbase + j);
        }
    }
    const float tinv = 1.0f / fmaxf(temp[0], 0.5f);

    // ---- phase (b): scores + softmax; thread owns m = j4*16 + mm (contiguous) ----
    {
        const float* kb = ws_k + b * (M_ * RC_);
        float sc[16];
        #pragma unroll
        for (int mm = 0; mm < 16; ++mm) {
            const int m = j4*16 + mm;
            const float4 k0 = *(const float4*)&kb[m*RC_ + 0];
            const float4 k1 = *(const float4*)&kb[m*RC_ + 4];
            const float4 k2 = *(const float4*)&kb[m*RC_ + 8];
            const float4 k3 = *(const float4*)&kb[m*RC_ + 12];
            float d = q[0].x*k0.x;
            d = fmaf(q[0].y, k0.y, d); d = fmaf(q[0].z, k0.z, d); d = fmaf(q[0].w, k0.w, d);
            d = fmaf(q[1].x, k1.x, d); d = fmaf(q[1].y, k1.y, d); d = fmaf(q[1].z, k1.z, d); d = fmaf(q[1].w, k1.w, d);
            d = fmaf(q[2].x, k2.x, d); d = fmaf(q[2].y, k2.y, d); d = fmaf(q[2].z, k2.z, d); d = fmaf(q[2].w, k2.w, d);
            d = fmaf(q[3].x, k3.x, d); d = fmaf(q[3].y, k3.y, d); d = fmaf(q[3].z, k3.z, d); d = fmaf(q[3].w, k3.w, d);
            sc[mm] = d * tinv;
        }
        float mx = sc[0];
        #pragma unroll
        for (int mm = 1; mm < 16; ++mm) mx = fmaxf(mx, sc[mm]);
        mx = fmaxf(mx, __shfl_xor(mx, 1)); mx = fmaxf(mx, __shfl_xor(mx, 2));
        float es = 0.0f;
        #pragma unroll
        for (int mm = 0; mm < 16; ++mm) { sc[mm] = expf(sc[mm] - mx); es += sc[mm]; }
        es += __shfl_xor(es, 1); es += __shfl_xor(es, 2);
        const float einv = 1.0f / es;
        float* aw = attn_out + (size_t)(b * N_ + n0 + r) * M_ + j4*16;
        #pragma unroll
        for (int mq = 0; mq < 4; ++mq) {
            float4 av;
            av.x = sc[mq*4+0]*einv; av.y = sc[mq*4+1]*einv;
            av.z = sc[mq*4+2]*einv; av.w = sc[mq*4+3]*einv;
            ((float4*)aw)[mq] = av;
        }
    }
}

// ---------------------------------------------------------------------------
// K_out: out = attn @ vg. 512 blocks x 4 row-tiles of 64; vg_s staged ONCE
//   per block (4x amortized vs monolith). attn tile staged TRANSPOSED
//   at_t[m][row] (stride 68) -> per m per wave: 1 ds_read_b128 (attn, 4 rows)
//   + 3 ds_read_b128 (vg) = minimal DS; VALU-dominated (96 cyc/m vs 48 DS).
//   No dependence on x. LDS 48K+17K = 65K -> 2 blocks/CU.
// ---------------------------------------------------------------------------
__global__ __launch_bounds__(256, 2) void k_out_kernel(
    const float* __restrict__ attn_g, const float* __restrict__ ws_vg,
    float* __restrict__ out)
{
    __shared__ float vg_s[M_ * C_];     // 48 KB
    __shared__ float at_t[M_ * ATS];    // 17 KB  [m][row]

    const int tid    = threadIdx.x;
    const int b      = blockIdx.x >> 6;
    const int n_base = (blockIdx.x & 63) * 256;

    // ---- stage vg once per block ----
    {
        const float4* src = (const float4*)(ws_vg + b * (M_ * C_));
        float4*       dst = (float4*)vg_s;
        #pragma unroll
        for (int i = 0; i < 12; ++i)
            dst[tid + 256 * i] = src[tid + 256 * i];
    }

    const int w0lane = tid & 63;
    const int rql = w0lane >> 4;       // 0..3
    const int cq  = w0lane & 15;       // 0..15
    const int wv  = tid >> 6;          // wave 0..3
    const int rs  = tid >> 4;          // staging row-low 0..15
    const int m0  = (tid & 15) * 4;    // staging m-slice

    for (int t = 0; t < 4; ++t) {
        const int n0 = n_base + t * 64;

        // ---- stage attn tile transposed: read [row][m] coalesced, write [m][row] ----
        #pragma unroll
        for (int rr = 0; rr < 4; ++rr) {
            const int row = rs + 16 * rr;
            const float4 g = *(const float4*)&attn_g[(size_t)(b * N_ + n0 + row) * M_ + m0];
            at_t[(m0+0)*ATS + row] = g.x;
            at_t[(m0+1)*ATS + row] = g.y;
            at_t[(m0+2)*ATS + row] = g.z;
            at_t[(m0+3)*ATS + row] = g.w;
        }
        __syncthreads();

        // ---- compute: lane (rql,cq) = 4 rows x 12 channels ----
        float4 ac0[3], ac1[3], ac2[3], ac3[3];
        #pragma unroll
        for (int tt = 0; tt < 3; ++tt) {
            ac0[tt] = make_float4(0.f,0.f,0.f,0.f);
            ac1[tt] = make_float4(0.f,0.f,0.f,0.f);
            ac2[tt] = make_float4(0.f,0.f,0.f,0.f);
            ac3[tt] = make_float4(0.f,0.f,0.f,0.f);
        }
        #pragma unroll 4
        for (int m = 0; m < M_; ++m) {
            const float4 av = *(const float4*)&at_t[m*ATS + 16*wv + 4*rql];
            const float4* vr = (const float4*)(vg_s + m*C_ + cq*12);
            #pragma unroll
            for (int tt = 0; tt < 3; ++tt) {
                const float4 v = vr[tt];
                FMA4(ac0[tt], av.x, v);
                FMA4(ac1[tt], av.y, v);
                FMA4(ac2[tt], av.z, v);
                FMA4(ac3[tt], av.w, v);
            }
        }
        const int row0 = 16*wv + 4*rql;
        float* o0 = out + (size_t)(b * N_ + n0 + row0) * C_ + cq*12;
        #pragma unroll
        for (int tt = 0; tt < 3; ++tt) {
            *(float4*)&o0[tt*4]        = ac0[tt];
            *(float4*)&o0[C_   + tt*4] = ac1[tt];
            *(float4*)&o0[2*C_ + tt*4] = ac2[tt];
            *(float4*)&o0[3*C_ + tt*4] = ac3[tt];
        }
        __syncthreads();   // protect at_t before next tile's staging
    }
}

// ---------------------------------------------------------------------------
extern "C" void kernel_launch(void* const* d_in, const int* in_sizes, int n_in,
                              void* d_out, int out_size, void* d_ws, size_t ws_size,
                              hipStream_t stream) {
    const float* x      = (const float*)d_in[0];
    const float* dict   = (const float*)d_in[1];
    const float* wq_w   = (const float*)d_in[4];
    const float* wq_b   = (const float*)d_in[5];
    const float* wk_w   = (const float*)d_in[6];
    const float* wk_b   = (const float*)d_in[7];
    const float* wv_w   = (const float*)d_in[8];
    const float* wv_b   = (const float*)d_in[9];
    const float* qn_g   = (const float*)d_in[10];
    const float* qn_b   = (const float*)d_in[11];
    const float* kn_g   = (const float*)d_in[12];
    const float* kn_b   = (const float*)d_in[13];
    const float* conv_w = (const float*)d_in[14];
    const float* conv_b = (const float*)d_in[15];
    const float* temp   = (const float*)d_in[16];

    float* out  = (float*)d_out;                          // (B,N,192)
    float* attn = out + (size_t)B_ * N_ * C_;             // (B,N,64)

    float* ws_vg = (float*)d_ws;                          // B*M*C = 98304 f
    float* ws_k  = ws_vg + B_ * M_ * C_;                  // 8192 f

    k_prep_kernel<<<B_ * M_,        256, 0, stream>>>(dict, wv_w, wv_b, conv_w, conv_b,
                                                      wk_w, wk_b, kn_g, kn_b, ws_vg, ws_k);
    k_q_kernel   <<<B_ * (N_ / M_), 256, 0, stream>>>(x, ws_k, wq_w, wq_b,
                                                      qn_g, qn_b, temp, attn);
    k_out_kernel <<<B_ * (N_ / 256), 256, 0, stream>>>(attn, ws_vg, out);
}

// Round 10
// 300.448 us; speedup vs baseline: 1.3057x; 1.3057x over previous
//
#include <hip/hip_runtime.h>
#include <math.h>

#define B_   8
#define N_   16384
#define M_   64
#define C_   192
#define RC_  16
#define CW   20    // wq_s row stride (floats): 16 + 4 pad -> 2-way bank max, 16B-aligned rows
#define ATS  68    // at_t row stride (floats): 16B-aligned, conflict-free reads

#define FMA4(acc, s, v) \
    acc.x = fmaf(s, v.x, acc.x); acc.y = fmaf(s, v.y, acc.y); \
    acc.z = fmaf(s, v.z, acc.z); acc.w = fmaf(s, v.w, acc.w)

// ---------------------------------------------------------------------------
// K_prep: fused  v = dict@wv+b -> conv3x1+GELU -> ws_vg ; k = l2n(LN(...)) -> ws_k
// (unchanged — verified correct)
// ---------------------------------------------------------------------------
__global__ __launch_bounds__(256) void k_prep_kernel(
    const float* __restrict__ dict,
    const float* __restrict__ wv_w, const float* __restrict__ wv_b,
    const float* __restrict__ conv_w, const float* __restrict__ conv_b,
    const float* __restrict__ wk_w, const float* __restrict__ wk_b,
    const float* __restrict__ kn_g, const float* __restrict__ kn_b,
    float* __restrict__ ws_vg, float* __restrict__ ws_k)
{
    const int b   = blockIdx.x >> 6;
    const int m   = blockIdx.x & 63;
    const int tid = threadIdx.x;
    const float* d0 = dict + (b * M_ + m) * C_;

    if (tid < 192) {
        const int c = tid;
        const bool hm = (m > 0), hp = (m < M_ - 1);
        const float* dm = hm ? d0 - C_ : d0;
        const float* dp = hp ? d0 + C_ : d0;
        float am = 0.f, ac = 0.f, ap = 0.f;
        #pragma unroll 4
        for (int d = 0; d < C_; ++d) {
            const float w = wv_w[d * C_ + c];
            am = fmaf(dm[d], w, am);
            ac = fmaf(d0[d], w, ac);
            ap = fmaf(dp[d], w, ap);
        }
        const float bia = wv_b[c];
        const float up = hm ? (am + bia) : 0.f;
        const float ct = ac + bia;
        const float dn = hp ? (ap + bia) : 0.f;
        float t = conv_b[c];
        t = fmaf(up, conv_w[c*9 + 1], t);
        t = fmaf(ct, conv_w[c*9 + 4], t);
        t = fmaf(dn, conv_w[c*9 + 7], t);
        ws_vg[(b * M_ + m) * C_ + c] = 0.5f * t * (1.0f + erff(t * 0.70710678118654752f));
    } else if (tid < 196) {
        const int j4 = tid - 192;
        const int c0 = j4 * 4;
        float a0 = wk_b[c0+0], a1 = wk_b[c0+1], a2 = wk_b[c0+2], a3 = wk_b[c0+3];
        #pragma unroll 4
        for (int d4 = 0; d4 < C_/4; ++d4) {
            const float4 xv = ((const float4*)d0)[d4];
            const float4 w0 = *(const float4*)&wk_w[(d4*4+0)*RC_ + c0];
            const float4 w1 = *(const float4*)&wk_w[(d4*4+1)*RC_ + c0];
            const float4 w2 = *(const float4*)&wk_w[(d4*4+2)*RC_ + c0];
            const float4 w3 = *(const float4*)&wk_w[(d4*4+3)*RC_ + c0];
            a0 = fmaf(xv.x, w0.x, a0); a1 = fmaf(xv.x, w0.y, a1); a2 = fmaf(xv.x, w0.z, a2); a3 = fmaf(xv.x, w0.w, a3);
            a0 = fmaf(xv.y, w1.x, a0); a1 = fmaf(xv.y, w1.y, a1); a2 = fmaf(xv.y, w1.z, a2); a3 = fmaf(xv.y, w1.w, a3);
            a0 = fmaf(xv.z, w2.x, a0); a1 = fmaf(xv.z, w2.y, a1); a2 = fmaf(xv.z, w2.z, a2); a3 = fmaf(xv.z, w2.w, a3);
            a0 = fmaf(xv.w, w3.x, a0); a1 = fmaf(xv.w, w3.y, a1); a2 = fmaf(xv.w, w3.z, a2); a3 = fmaf(xv.w, w3.w, a3);
        }
        float s  = a0 + a1 + a2 + a3;
        float ss = a0*a0 + a1*a1 + a2*a2 + a3*a3;
        s  += __shfl_xor(s, 1);  s  += __shfl_xor(s, 2);
        ss += __shfl_xor(ss, 1); ss += __shfl_xor(ss, 2);
        const float mu   = s * (1.0f/16.0f);
        const float var  = ss * (1.0f/16.0f) - mu*mu;
        const float rstd = rsqrtf(var + 1e-5f);
        const float4 g4 = *(const float4*)&kn_g[c0];
        const float4 b4 = *(const float4*)&kn_b[c0];
        const float y0 = (a0 - mu) * rstd * g4.x + b4.x;
        const float y1 = (a1 - mu) * rstd * g4.y + b4.y;
        const float y2 = (a2 - mu) * rstd * g4.z + b4.z;
        const float y3 = (a3 - mu) * rstd * g4.w + b4.w;
        float n2 = y0*y0 + y1*y1 + y2*y2 + y3*y3;
        n2 += __shfl_xor(n2, 1); n2 += __shfl_xor(n2, 2);
        const float inv = 1.0f / fmaxf(sqrtf(n2), 1e-12f);
        float4 o; o.x = y0*inv; o.y = y1*inv; o.z = y2*inv; o.w = y3*inv;
        *(float4*)&ws_k[(b * M_ + m) * RC_ + c0] = o;
    }
}

// ---------------------------------------------------------------------------
// K_main v2 — built for the VMEM-instruction model (≈38 clk/instr/CU):
//   r8 had 281 VMEM instrs/wave (48 redundant x + 192 wq from L1) = 142 µs.
//   v2 cuts to ~56: wq_w read from LDS (DS pipe), x cooperatively loaded
//   (12 instrs = the 12 KB/wave minimum) with d-split partial sums + quad
//   reduction (every lane ends with the FULL q row -> LN/l2norm shuffle-free).
//   wq_b/qn_g/qn_b indexed by compile-time c -> scalar (SMEM) loads.
//   LDS: vg 48K + k 4K + u_s 17K = 69 KB (2 blocks/CU). u_s is wq[192][20]
//   during phase (a), then reused as at_t[64][68] (attn transposed) after the
//   second barrier; at_t traffic is intra-wave (cols 16wv..16wv+15).
//   Phase (c): per m = 1 at_t b128 + 3 vg b128, conflict-free.
// ---------------------------------------------------------------------------
__global__ __launch_bounds__(256, 2) void k_main_kernel(
    const float* __restrict__ x, const float* __restrict__ ws_k,
    const float* __restrict__ ws_vg,
    const float* __restrict__ wq_w, const float* __restrict__ wq_b,
    const float* __restrict__ qn_g, const float* __restrict__ qn_b,
    const float* __restrict__ temp,
    float* __restrict__ out, float* __restrict__ attn_out)
{
    __shared__ float vg_s[M_ * C_];    // 12288 f = 48 KB
    __shared__ float k_s[M_ * RC_];    //  1024 f =  4 KB
    __shared__ float u_s[M_ * ATS];    //  4352 f = 17 KB: wq[192][20] then at_t[64][68]

    const int tid  = threadIdx.x;
    const int b    = blockIdx.x >> 8;
    const int n0   = (blockIdx.x & 255) * M_;
    const int lane = tid & 63;
    const int r    = tid >> 2;        // 0..63 (row in tile)
    const int j4   = tid & 3;
    const int wv   = tid >> 6;        // wave 0..3

    // ---- stage: vg (12), k (1), wq (3 loads -> stride-20 LDS) ----
    {
        const float4* vgb4 = (const float4*)(ws_vg + b * (M_ * C_));
        #pragma unroll
        for (int i = 0; i < 12; ++i)
            ((float4*)vg_s)[tid + 256 * i] = vgb4[tid + 256 * i];
        ((float4*)k_s)[tid] = ((const float4*)(ws_k + b * (M_ * RC_)))[tid];
        #pragma unroll
        for (int i = 0; i < 3; ++i) {
            const int idx = tid + 256 * i;              // 0..767 float4-chunks
            const float4 w = ((const float4*)wq_w)[idx];
            *(float4*)&u_s[(idx >> 2) * CW + (idx & 3) * 4] = w;
        }
    }
    __syncthreads();   // barrier 1: wq_s/k_s/vg_s ready

    // ---- phase (a): d-split projection. lane j4 owns x-chunks 4i+j4 ----
    const float4* xr4 = (const float4*)(x + (size_t)(b * N_ + n0 + r) * C_);
    float acc[16];
    #pragma unroll
    for (int c = 0; c < 16; ++c) acc[c] = 0.f;
    #pragma unroll
    for (int i = 0; i < 12; ++i) {
        const float4 xv = xr4[i*4 + j4];                // 12 VMEM total (no redundancy)
        const float* wr = &u_s[(i*16 + j4*4) * CW];     // 4 w-rows, broadcast across quads
        #define WROW(xd, row) { \
            const float4 w0 = *(const float4*)&wr[(row)*CW + 0]; \
            const float4 w1 = *(const float4*)&wr[(row)*CW + 4]; \
            const float4 w2 = *(const float4*)&wr[(row)*CW + 8]; \
            const float4 w3 = *(const float4*)&wr[(row)*CW + 12]; \
            acc[0]=fmaf(xd,w0.x,acc[0]); acc[1]=fmaf(xd,w0.y,acc[1]); acc[2]=fmaf(xd,w0.z,acc[2]); acc[3]=fmaf(xd,w0.w,acc[3]); \
            acc[4]=fmaf(xd,w1.x,acc[4]); acc[5]=fmaf(xd,w1.y,acc[5]); acc[6]=fmaf(xd,w1.z,acc[6]); acc[7]=fmaf(xd,w1.w,acc[7]); \
            acc[8]=fmaf(xd,w2.x,acc[8]); acc[9]=fmaf(xd,w2.y,acc[9]); acc[10]=fmaf(xd,w2.z,acc[10]); acc[11]=fmaf(xd,w2.w,acc[11]); \
            acc[12]=fmaf(xd,w3.x,acc[12]); acc[13]=fmaf(xd,w3.y,acc[13]); acc[14]=fmaf(xd,w3.z,acc[14]); acc[15]=fmaf(xd,w3.w,acc[15]); }
        WROW(xv.x, 0) WROW(xv.y, 1) WROW(xv.z, 2) WROW(xv.w, 3)
        #undef WROW
    }
    // quad reduction -> every lane holds the full 16-comp sum; LN/l2n local
    float qv[16];
    {
        #pragma unroll
        for (int c = 0; c < 16; ++c) {
            acc[c] += __shfl_xor(acc[c], 1);
            acc[c] += __shfl_xor(acc[c], 2);
            acc[c] += wq_b[c];                          // uniform -> s_load
        }
        float s = 0.f, ss = 0.f;
        #pragma unroll
        for (int c = 0; c < 16; ++c) { s += acc[c]; ss += acc[c]*acc[c]; }
        const float mu   = s * (1.0f/16.0f);
        const float var  = ss * (1.0f/16.0f) - mu*mu;
        const float rstd = rsqrtf(var + 1e-5f);
        float n2 = 0.f;
        #pragma unroll
        for (int c = 0; c < 16; ++c) {
            const float y = (acc[c] - mu) * rstd * qn_g[c] + qn_b[c];
            qv[c] = y; n2 += y*y;
        }
        const float inv = 1.0f / fmaxf(sqrtf(n2), 1e-12f);
        #pragma unroll
        for (int c = 0; c < 16; ++c) qv[c] *= inv;
    }
    const float tinv = 1.0f / fmaxf(temp[0], 0.5f);

    __syncthreads();   // barrier 2: all wq_s reads done -> u_s becomes at_t

    // ---- phase (b): scores + softmax; thread owns m = 4*mm + j4 (2-way k_s) ----
    {
        float sc[16];
        #pragma unroll
        for (int mm = 0; mm < 16; ++mm) {
            const int m = mm*4 + j4;
            const float4 k0 = *(const float4*)&k_s[m*RC_ + 0];
            const float4 k1 = *(const float4*)&k_s[m*RC_ + 4];
            const float4 k2 = *(const float4*)&k_s[m*RC_ + 8];
            const float4 k3 = *(const float4*)&k_s[m*RC_ + 12];
            float d = qv[0]*k0.x;
            d = fmaf(qv[1], k0.y, d); d = fmaf(qv[2], k0.z, d); d = fmaf(qv[3], k0.w, d);
            d = fmaf(qv[4], k1.x, d); d = fmaf(qv[5], k1.y, d); d = fmaf(qv[6], k1.z, d); d = fmaf(qv[7], k1.w, d);
            d = fmaf(qv[8], k2.x, d); d = fmaf(qv[9], k2.y, d); d = fmaf(qv[10], k2.z, d); d = fmaf(qv[11], k2.w, d);
            d = fmaf(qv[12], k3.x, d); d = fmaf(qv[13], k3.y, d); d = fmaf(qv[14], k3.z, d); d = fmaf(qv[15], k3.w, d);
            sc[mm] = d * tinv;
        }
        float mx = sc[0];
        #pragma unroll
        for (int mm = 1; mm < 16; ++mm) mx = fmaxf(mx, sc[mm]);
        mx = fmaxf(mx, __shfl_xor(mx, 1)); mx = fmaxf(mx, __shfl_xor(mx, 2));
        float es = 0.0f;
        #pragma unroll
        for (int mm = 0; mm < 16; ++mm) { sc[mm] = expf(sc[mm] - mx); es += sc[mm]; }
        es += __shfl_xor(es, 1); es += __shfl_xor(es, 2);
        const float einv = 1.0f / es;
        float* aw = attn_out + (size_t)(b * N_ + n0 + r) * M_;
        #pragma unroll
        for (int mm = 0; mm < 16; ++mm) {
            const float p = sc[mm] * einv;
            aw[mm*4 + j4] = p;                    // global attn (16 scalar stores)
            u_s[(mm*4 + j4)*ATS + r] = p;         // at_t[m][r] — intra-wave columns
        }
    }
    // no barrier: at_t cols [16wv,16wv+16) written & read by wave wv only

    // ---- phase (c): out = attn @ vg; lane (rql,cq) = 4 rows x 12 channels ----
    {
        const int rql = lane >> 4;           // 0..3
        const int cq  = lane & 15;           // 0..15
        float4 ac0[3], ac1[3], ac2[3], ac3[3];
        #pragma unroll
        for (int t = 0; t < 3; ++t) {
            ac0[t] = make_float4(0.f,0.f,0.f,0.f);
            ac1[t] = make_float4(0.f,0.f,0.f,0.f);
            ac2[t] = make_float4(0.f,0.f,0.f,0.f);
            ac3[t] = make_float4(0.f,0.f,0.f,0.f);
        }
        #pragma unroll 4
        for (int m = 0; m < M_; ++m) {
            const float4 av = *(const float4*)&u_s[m*ATS + 16*wv + 4*rql];
            const float4* vr = (const float4*)(vg_s + m*C_ + cq*12);
            #pragma unroll
            for (int t = 0; t < 3; ++t) {
                const float4 v = vr[t];
                FMA4(ac0[t], av.x, v);
                FMA4(ac1[t], av.y, v);
                FMA4(ac2[t], av.z, v);
                FMA4(ac3[t], av.w, v);
            }
        }
        const int row0 = 16*wv + 4*rql;
        float* o0 = out + (size_t)(b * N_ + n0 + row0) * C_ + cq*12;
        #pragma unroll
        for (int t = 0; t < 3; ++t) {
            *(float4*)&o0[t*4]        = ac0[t];
            *(float4*)&o0[C_   + t*4] = ac1[t];
            *(float4*)&o0[2*C_ + t*4] = ac2[t];
            *(float4*)&o0[3*C_ + t*4] = ac3[t];
        }
    }
}

// ---------------------------------------------------------------------------
extern "C" void kernel_launch(void* const* d_in, const int* in_sizes, int n_in,
                              void* d_out, int out_size, void* d_ws, size_t ws_size,
                              hipStream_t stream) {
    const float* x      = (const float*)d_in[0];
    const float* dict   = (const float*)d_in[1];
    const float* wq_w   = (const float*)d_in[4];
    const float* wq_b   = (const float*)d_in[5];
    const float* wk_w   = (const float*)d_in[6];
    const float* wk_b   = (const float*)d_in[7];
    const float* wv_w   = (const float*)d_in[8];
    const float* wv_b   = (const float*)d_in[9];
    const float* qn_g   = (const float*)d_in[10];
    const float* qn_b   = (const float*)d_in[11];
    const float* kn_g   = (const float*)d_in[12];
    const float* kn_b   = (const float*)d_in[13];
    const float* conv_w = (const float*)d_in[14];
    const float* conv_b = (const float*)d_in[15];
    const float* temp   = (const float*)d_in[16];

    float* out  = (float*)d_out;                          // (B,N,192)
    float* attn = out + (size_t)B_ * N_ * C_;             // (B,N,64)

    float* ws_vg = (float*)d_ws;                          // B*M*C = 98304 f
    float* ws_k  = ws_vg + B_ * M_ * C_;                  // 8192 f

    k_prep_kernel<<<B_ * M_,        256, 0, stream>>>(dict, wv_w, wv_b, conv_w, conv_b,
                                                      wk_w, wk_b, kn_g, kn_b, ws_vg, ws_k);
    k_main_kernel<<<B_ * (N_ / M_), 256, 0, stream>>>(x, ws_k, ws_vg, wq_w, wq_b,
                                                      qn_g, qn_b, temp, out, attn);
}